// Round 1
// baseline (236.829 us; speedup 1.0000x reference)
//
#include <hip/hip_runtime.h>
#include <math.h>

// Problem constants (match reference exactly)
#define BROWS 1024
#define NPTS  32768
#define MPTS  16384          // NPTS/2 (complex FFT size via real-packing trick)
#define LOG2M 14
#define NTHR  512
#define MIN_IDX 1092         // argmin |f - 40/60|, f[k]=k*10/16384 (exact fp32 grid)
#define MAX_IDX 6827         // argmin |f - 250/60|
#define DENOMF  5732.0f      // MAX_IDX - MIN_IDX - 3

// Recover |X[k]|^2 (ortho-normalized) from the packed complex FFT result.
// z holds FFT of z[m]=x[2m]+i*x[2m+1] in BIT-REVERSED order (DIF output).
__device__ inline float bin_power(const float2* __restrict__ z, int k) {
    int rk  = (int)(__brev((unsigned)k)        >> (32 - LOG2M));
    int rmk = (int)(__brev((unsigned)(MPTS-k)) >> (32 - LOG2M));
    float2 a = z[rk];
    float2 b = z[rmk];
    float bx = b.x, by = -b.y;                    // conj(Z[M-k])
    float ex = 0.5f * (a.x + bx), ey = 0.5f * (a.y + by);   // Xe[k]
    float dx = a.x - bx,          dy = a.y - by;
    float ox = 0.5f * dy,         oy = -0.5f * dx;          // Xo[k] = -i/2 * d
    // X[k] = Xe + e^{-2pi i k/N} * Xo
    float ang = (-6.283185307179586f / (float)NPTS) * (float)k;
    float c, sn;
    sincosf(ang, &sn, &c);
    float Xx = ex + ox * c - oy * sn;
    float Xy = ey + ox * sn + oy * c;
    return (Xx * Xx + Xy * Xy) * (1.0f / (float)NPTS);      // ortho: |X|^2 / N
}

__global__ __launch_bounds__(NTHR) void snr_row_kernel(
        const float* __restrict__ outs,
        const float* __restrict__ targets,
        float* __restrict__ row_loss) {
    __shared__ float2 z[MPTS];          // 128 KiB
    __shared__ float  red[NTHR / 64];

    const int b   = blockIdx.x;
    const int tid = threadIdx.x;
    const float* row = outs + (size_t)b * NPTS;

    // ---- Load row, pack real pairs into complex: z[m] = x[2m] + i x[2m+1]
    for (int i = tid; i < NPTS / 4; i += NTHR) {
        float4 v = *reinterpret_cast<const float4*>(row + 4 * i);
        z[2 * i]     = make_float2(v.x, v.y);
        z[2 * i + 1] = make_float2(v.z, v.w);
    }
    __syncthreads();

    // ---- In-place radix-2 DIF FFT (size MPTS), natural in -> bit-reversed out
    const float w0 = -6.283185307179586f / (float)MPTS;   // -2pi/M
    for (int s = 0; s < LOG2M; ++s) {
        const int halfLog = LOG2M - 1 - s;
        const int half    = 1 << halfLog;
        for (int q = tid; q < MPTS / 2; q += NTHR) {
            int t   = q & (half - 1);
            int blk = q >> halfLog;
            int i0  = (blk << (halfLog + 1)) + t;
            int i1  = i0 + half;
            float2 u = z[i0];
            float2 v = z[i1];
            float sx = u.x + v.x, sy = u.y + v.y;
            float dx = u.x - v.x, dy = u.y - v.y;
            int j = t << s;                     // twiddle exponent: W_M^(t * M/len)
            float ang = w0 * (float)j;
            float c, sn;
            sincosf(ang, &sn, &c);
            z[i0] = make_float2(sx, sy);
            z[i1] = make_float2(dx * c - dy * sn, dx * sn + dy * c);
        }
        __syncthreads();
    }

    // ---- Sum band power [MIN_IDX, MAX_IDX)
    float local = 0.0f;
    for (int k = MIN_IDX + tid; k < MAX_IDX; k += NTHR)
        local += bin_power(z, k);

    // wave reduce (64 lanes)
    for (int off = 32; off; off >>= 1) local += __shfl_down(local, off);
    const int lane = tid & 63, wave = tid >> 6;
    if (lane == 0) red[wave] = local;
    __syncthreads();

    if (tid == 0) {
        float S = 0.0f;
        #pragma unroll
        for (int w = 0; w < NTHR / 64; ++w) S += red[w];

        // ref_idx: argmin_k |f[k] - t|, f[k] = k * (10/16384) exact in fp32.
        // Candidates k0 = floor(t/step), k0+1; compare fp32 distances like jnp
        // (tie -> lower index).
        float tgt = targets[b];
        double kd = (double)tgt * (16384.0 / 10.0);
        int k0 = (int)kd;                       // t>0 so trunc == floor
        const float stepf = 10.0f / 16384.0f;   // exactly representable
        float f0 = (float)k0 * stepf;           // exact products (<=24 bits)
        float f1 = (float)(k0 + 1) * stepf;
        float d0 = fabsf(f0 - tgt);
        float d1 = fabsf(f1 - tgt);
        int r = (d0 <= d1) ? k0 : (k0 + 1);

        float pm1 = bin_power(z, r - 1);
        float p0  = bin_power(z, r);
        float pp1 = bin_power(z, r + 1);
        float other_avg = (S - pm1 - p0 - pp1) * (1.0f / DENOMF);
        row_loss[b] = -10.0f * log10f(p0 / other_avg);
    }
}

__global__ __launch_bounds__(256) void snr_reduce_kernel(
        const float* __restrict__ row_loss, float* __restrict__ out) {
    __shared__ float red[4];
    float s = 0.0f;
    for (int i = threadIdx.x; i < BROWS; i += 256) s += row_loss[i];
    for (int off = 32; off; off >>= 1) s += __shfl_down(s, off);
    if ((threadIdx.x & 63) == 0) red[threadIdx.x >> 6] = s;
    __syncthreads();
    if (threadIdx.x == 0)
        out[0] = (red[0] + red[1] + red[2] + red[3]) * (1.0f / (float)BROWS);
}

extern "C" void kernel_launch(void* const* d_in, const int* in_sizes, int n_in,
                              void* d_out, int out_size, void* d_ws, size_t ws_size,
                              hipStream_t stream) {
    const float* outs    = (const float*)d_in[0];
    const float* targets = (const float*)d_in[1];
    float* ws  = (float*)d_ws;    // 1024 per-row losses
    float* out = (float*)d_out;

    snr_row_kernel<<<BROWS, NTHR, 0, stream>>>(outs, targets, ws);
    snr_reduce_kernel<<<1, 256, 0, stream>>>(ws, out);
}

// Round 2
// 109.848 us; speedup vs baseline: 2.1560x; 2.1560x over previous
//
#include <hip/hip_runtime.h>
#include <math.h>

// Problem constants (match reference exactly)
#define BROWS 1024
#define NPTS  32768
#define MPTS  16384          // NPTS/2 (complex FFT size via real-packing trick)
#define LOG2M 14
#define NTHR  512
#define MIN_IDX 1092         // argmin |f - 40/60|, f[k]=k*10/16384 (exact fp32 grid)
#define MAX_IDX 6827         // argmin |f - 250/60|
#define DENOMF  5732.0f      // MAX_IDX - MIN_IDX - 3

// LDS pad-swizzle: one float2 pad per 16 elements breaks all 4^k strides
// down to the b64 bank floor (hand-verified for strides 1,4,16,64,256,...).
#define PADI(i) ((i) + ((i) >> 4))
#define ZLEN    (MPTS + (MPTS >> 4))   // 17408 float2 = 136 KiB

__device__ inline float2 cmul(float x, float y, float c, float s) {
    return make_float2(x * c - y * s, x * s + y * c);
}

// Recover |X[k]|^2 (ortho-normalized) from the packed complex FFT result.
// z holds FFT of z[m]=x[2m]+i*x[2m+1] in BIT-REVERSED order (radix-4 DIF
// derived as fused pairs of radix-2 DIF stages -> same bit-reversal).
__device__ inline float bin_power(const float2* __restrict__ z, int k) {
    int rk  = (int)(__brev((unsigned)k)        >> (32 - LOG2M));
    int rmk = (int)(__brev((unsigned)(MPTS-k)) >> (32 - LOG2M));
    float2 a = z[PADI(rk)];
    float2 b = z[PADI(rmk)];
    float bx = b.x, by = -b.y;                    // conj(Z[M-k])
    float ex = 0.5f * (a.x + bx), ey = 0.5f * (a.y + by);   // Xe[k]
    float dx = a.x - bx,          dy = a.y - by;
    float ox = 0.5f * dy,         oy = -0.5f * dx;          // Xo[k] = -i/2 * d
    // X[k] = Xe + e^{-2pi i k/N} * Xo
    float ang = (-6.283185307179586f / (float)NPTS) * (float)k;
    float c, sn;
    __sincosf(ang, &sn, &c);
    float Xx = ex + ox * c - oy * sn;
    float Xy = ey + ox * sn + oy * c;
    return (Xx * Xx + Xy * Xy) * (1.0f / (float)NPTS);      // ortho: |X|^2 / N
}

__global__ __launch_bounds__(NTHR) void snr_row_kernel(
        const float* __restrict__ outs,
        const float* __restrict__ targets,
        float* __restrict__ row_loss) {
    __shared__ float2 z[ZLEN];          // 136 KiB (padded)
    __shared__ float  red[NTHR / 64];

    const int b   = blockIdx.x;
    const int tid = threadIdx.x;
    const float* row = outs + (size_t)b * NPTS;

    // ---- Load row, pack real pairs into complex: z[m] = x[2m] + i x[2m+1]
    for (int i = tid; i < NPTS / 4; i += NTHR) {
        float4 v = *reinterpret_cast<const float4*>(row + 4 * i);
        z[PADI(2 * i)]     = make_float2(v.x, v.y);
        z[PADI(2 * i + 1)] = make_float2(v.z, v.w);
    }
    __syncthreads();

    // ---- In-place radix-4 DIF FFT (size MPTS = 4^7), natural in,
    //      14-bit bit-reversed out (identical ordering to radix-2 DIF x14).
    const float w0 = -6.283185307179586f / (float)MPTS;   // -2pi/M
    for (int r = 0; r < 7; ++r) {
        const int l2q = 2 * (6 - r);
        const int q   = 1 << l2q;
        const float jscale = w0 * (float)(1 << (2 * r)); // angle per unit t
        #pragma unroll
        for (int it = 0; it < (MPTS / 4) / NTHR; ++it) {
            const int idx = tid + it * NTHR;
            const int t   = idx & (q - 1);
            const int blk = idx >> l2q;
            const int i0  = (blk << (l2q + 2)) + t;

            float2 a = z[PADI(i0)];
            float2 bb = z[PADI(i0 + q)];
            float2 c = z[PADI(i0 + 2 * q)];
            float2 d = z[PADI(i0 + 3 * q)];

            // Twiddles: W^j, W^2j (=square), W^3j (=product), j = t*4^r
            float a1 = jscale * (float)t;
            float c1, s1;
            __sincosf(a1, &s1, &c1);
            float c2 = c1 * c1 - s1 * s1, s2 = 2.0f * c1 * s1;
            float c3 = c1 * c2 - s1 * s2, s3 = c1 * s2 + s1 * c2;

            float e0x = a.x + c.x,  e0y = a.y + c.y;   // a+c
            float e1x = a.x - c.x,  e1y = a.y - c.y;   // a-c
            float e2x = bb.x + d.x, e2y = bb.y + d.y;  // b+d
            float e3x = bb.x - d.x, e3y = bb.y - d.y;  // b-d

            // out0 = (a+c)+(b+d)                      -> i0      (no twiddle)
            // out1 = ((a+c)-(b+d)) * W^2j             -> i0+q
            // out2 = ((a-c) - i(b-d)) * W^j           -> i0+2q
            // out3 = ((a-c) + i(b-d)) * W^3j          -> i0+3q
            z[PADI(i0)]         = make_float2(e0x + e2x, e0y + e2y);
            z[PADI(i0 + q)]     = cmul(e0x - e2x, e0y - e2y, c2, s2);
            z[PADI(i0 + 2 * q)] = cmul(e1x + e3y, e1y - e3x, c1, s1);
            z[PADI(i0 + 3 * q)] = cmul(e1x - e3y, e1y + e3x, c3, s3);
        }
        __syncthreads();
    }

    // ---- Sum band power [MIN_IDX, MAX_IDX)
    float local = 0.0f;
    for (int k = MIN_IDX + tid; k < MAX_IDX; k += NTHR)
        local += bin_power(z, k);

    // wave reduce (64 lanes)
    for (int off = 32; off; off >>= 1) local += __shfl_down(local, off);
    const int lane = tid & 63, wave = tid >> 6;
    if (lane == 0) red[wave] = local;
    __syncthreads();

    if (tid == 0) {
        float S = 0.0f;
        #pragma unroll
        for (int w = 0; w < NTHR / 64; ++w) S += red[w];

        // ref_idx: argmin_k |f[k] - t|, f[k] = k * (10/16384) exact in fp32.
        float tgt = targets[b];
        double kd = (double)tgt * (16384.0 / 10.0);
        int k0 = (int)kd;                       // t>0 so trunc == floor
        const float stepf = 10.0f / 16384.0f;   // exactly representable
        float f0 = (float)k0 * stepf;           // exact products (<=24 bits)
        float f1 = (float)(k0 + 1) * stepf;
        float d0 = fabsf(f0 - tgt);
        float d1 = fabsf(f1 - tgt);
        int r = (d0 <= d1) ? k0 : (k0 + 1);

        float pm1 = bin_power(z, r - 1);
        float p0  = bin_power(z, r);
        float pp1 = bin_power(z, r + 1);
        float other_avg = (S - pm1 - p0 - pp1) * (1.0f / DENOMF);
        row_loss[b] = -10.0f * log10f(p0 / other_avg);
    }
}

__global__ __launch_bounds__(256) void snr_reduce_kernel(
        const float* __restrict__ row_loss, float* __restrict__ out) {
    __shared__ float red[4];
    float s = 0.0f;
    for (int i = threadIdx.x; i < BROWS; i += 256) s += row_loss[i];
    for (int off = 32; off; off >>= 1) s += __shfl_down(s, off);
    if ((threadIdx.x & 63) == 0) red[threadIdx.x >> 6] = s;
    __syncthreads();
    if (threadIdx.x == 0)
        out[0] = (red[0] + red[1] + red[2] + red[3]) * (1.0f / (float)BROWS);
}

extern "C" void kernel_launch(void* const* d_in, const int* in_sizes, int n_in,
                              void* d_out, int out_size, void* d_ws, size_t ws_size,
                              hipStream_t stream) {
    const float* outs    = (const float*)d_in[0];
    const float* targets = (const float*)d_in[1];
    float* ws  = (float*)d_ws;    // 1024 per-row losses
    float* out = (float*)d_out;

    snr_row_kernel<<<BROWS, NTHR, 0, stream>>>(outs, targets, ws);
    snr_reduce_kernel<<<1, 256, 0, stream>>>(ws, out);
}

// Round 3
// 78.829 us; speedup vs baseline: 3.0043x; 1.3935x over previous
//
#include <hip/hip_runtime.h>
#include <math.h>

// Problem constants (match reference exactly)
#define BROWS 1024
#define NPTS  32768
#define MPTS  16384          // NPTS/2 (complex FFT size via real-packing trick)
#define LOG2M 14
#define NTHR  1024
#define MIN_IDX 1092         // argmin |f - 40/60|, f[k]=k*10/16384 (exact fp32 grid)
#define MAX_IDX 6827         // argmin |f - 250/60|
#define DENOMF  5732.0f      // MAX_IDX - MIN_IDX - 3
#define W0 (-6.283185307179586f / (float)MPTS)

// LDS pad-swizzle: one float2 pad per 16 elements keeps all 4^k strides at
// the b64 bank floor (hand-verified for strides 1,2,4,16,64,256,1024).
#define PADI(i) ((i) + ((i) >> 4))
#define ZLEN    (MPTS + (MPTS >> 4))   // 17408 float2 = 136 KiB

// Radix-4 DIF butterfly, in-place on 4 regs; slot order (+0,+q,+2q,+3q).
// Twiddles: p1 *= (c2,s2)=W^2j, p2 *= (c1,s1)=W^j, p3 *= (c3,s3)=W^3j.
__device__ inline void bfly4(float2& p0, float2& p1, float2& p2, float2& p3,
                             float c1, float s1, float c2, float s2,
                             float c3, float s3) {
    float e0x = p0.x + p2.x, e0y = p0.y + p2.y;
    float e1x = p0.x - p2.x, e1y = p0.y - p2.y;
    float e2x = p1.x + p3.x, e2y = p1.y + p3.y;
    float e3x = p1.x - p3.x, e3y = p1.y - p3.y;
    float o1x = e0x - e2x, o1y = e0y - e2y;
    float o2x = e1x + e3y, o2y = e1y - e3x;
    float o3x = e1x - e3y, o3y = e1y + e3x;
    p0 = make_float2(e0x + e2x, e0y + e2y);
    p1 = make_float2(o1x * c2 - o1y * s2, o1x * s2 + o1y * c2);
    p2 = make_float2(o2x * c1 - o2y * s1, o2x * s1 + o2y * c1);
    p3 = make_float2(o3x * c3 - o3y * s3, o3x * s3 + o3y * c3);
}

// Fused pair of radix-4 DIF stages (global stage indices R and R+1) done in
// registers: radix-16 with one LDS round trip. L2S = log2(q2), q2 = 4^(6-R-1).
// Bit-exact same ordering/twiddles as running the two radix-4 stages apart.
template<int R, int L2S>
__device__ inline void fused16(float2* __restrict__ z, int tid) {
    const int q2  = 1 << L2S;
    const int t   = tid & (q2 - 1);
    const int blk = tid >> L2S;
    const int i0  = (blk << (L2S + 4)) + t;

    float2 x[16];
    #pragma unroll
    for (int j = 0; j < 16; ++j) x[j] = z[PADI(i0 + (j << L2S))];

    const float A1 = W0 * (float)(1 << (2 * R));
    // Stage R: span q1=4*q2; sub-butterfly c on (x[c],x[c+4],x[c+8],x[c+12]),
    // twiddle exponent t1 = c*q2 + t.
    #pragma unroll
    for (int c = 0; c < 4; ++c) {
        float a1 = A1 * (float)((c << L2S) + t);
        float c1, s1; __sincosf(a1, &s1, &c1);
        float c2 = c1 * c1 - s1 * s1, s2 = 2.0f * c1 * s1;
        float c3 = c1 * c2 - s1 * s2, s3 = c1 * s2 + s1 * c2;
        bfly4(x[c], x[c + 4], x[c + 8], x[c + 12], c1, s1, c2, s2, c3, s3);
    }
    // Stage R+1: span q2; groups are consecutive reg quads, exponent t.
    {
        float a1 = A1 * 4.0f * (float)t;
        float c1, s1; __sincosf(a1, &s1, &c1);
        float c2 = c1 * c1 - s1 * s1, s2 = 2.0f * c1 * s1;
        float c3 = c1 * c2 - s1 * s2, s3 = c1 * s2 + s1 * c2;
        #pragma unroll
        for (int g = 0; g < 4; ++g)
            bfly4(x[4 * g], x[4 * g + 1], x[4 * g + 2], x[4 * g + 3],
                  c1, s1, c2, s2, c3, s3);
    }
    #pragma unroll
    for (int j = 0; j < 16; ++j) z[PADI(i0 + (j << L2S))] = x[j];
}

// Recover |X[k]|^2 (ortho-normalized) from the packed complex FFT result
// (bit-reversed storage).
__device__ inline float bin_power(const float2* __restrict__ z, int k) {
    int rk  = (int)(__brev((unsigned)k)        >> (32 - LOG2M));
    int rmk = (int)(__brev((unsigned)(MPTS-k)) >> (32 - LOG2M));
    float2 a = z[PADI(rk)];
    float2 b = z[PADI(rmk)];
    float bx = b.x, by = -b.y;                    // conj(Z[M-k])
    float ex = 0.5f * (a.x + bx), ey = 0.5f * (a.y + by);   // Xe[k]
    float dx = a.x - bx,          dy = a.y - by;
    float ox = 0.5f * dy,         oy = -0.5f * dx;          // Xo[k] = -i/2 * d
    float ang = (-6.283185307179586f / (float)NPTS) * (float)k;
    float c, sn;
    __sincosf(ang, &sn, &c);
    float Xx = ex + ox * c - oy * sn;
    float Xy = ey + ox * sn + oy * c;
    return (Xx * Xx + Xy * Xy) * (1.0f / (float)NPTS);      // ortho: |X|^2 / N
}

__global__ __launch_bounds__(NTHR, 1) void snr_row_kernel(
        const float* __restrict__ outs,
        const float* __restrict__ targets,
        float* __restrict__ row_loss) {
    __shared__ float2 z[ZLEN];          // 136 KiB (padded)
    __shared__ float  red[NTHR / 64];

    const int b   = blockIdx.x;
    const int tid = threadIdx.x;
    const float* row = outs + (size_t)b * NPTS;

    // ---- Load row, pack real pairs into complex: z[m] = x[2m] + i x[2m+1]
    #pragma unroll
    for (int it = 0; it < (NPTS / 4) / NTHR; ++it) {
        int i = tid + it * NTHR;
        float4 v = *reinterpret_cast<const float4*>(row + 4 * i);
        z[PADI(2 * i)]     = make_float2(v.x, v.y);
        z[PADI(2 * i + 1)] = make_float2(v.z, v.w);
    }
    __syncthreads();

    // ---- In-place DIF FFT, size 16384 = (radix-16)^3 * radix-4,
    //      natural in -> 14-bit bit-reversed out.
    fused16<0, 10>(z, tid); __syncthreads();
    fused16<2, 6>(z, tid);  __syncthreads();
    fused16<4, 2>(z, tid);  __syncthreads();
    // Final radix-4 stage (R=6, q=1): t==0 -> all twiddles are 1.
    #pragma unroll
    for (int it = 0; it < (MPTS / 4) / NTHR; ++it) {
        int i0 = (tid + it * NTHR) << 2;
        float2 a = z[PADI(i0)], bb = z[PADI(i0 + 1)];
        float2 c = z[PADI(i0 + 2)], d = z[PADI(i0 + 3)];
        bfly4(a, bb, c, d, 1.0f, 0.0f, 1.0f, 0.0f, 1.0f, 0.0f);
        z[PADI(i0)] = a;     z[PADI(i0 + 1)] = bb;
        z[PADI(i0 + 2)] = c; z[PADI(i0 + 3)] = d;
    }
    __syncthreads();

    // ---- Band power sum [MIN_IDX, MAX_IDX), conflict-free gather:
    // k = (lane<<8)|m  =>  brev14(k) = (brev8(m)<<6)|brev6(lane): each wave
    // read is a permutation of 64 consecutive LDS elements (bank floor).
    const int lane = tid & 63, wave = tid >> 6;
    float local = 0.0f;
    for (int m = wave; m < 256; m += NTHR / 64) {
        int k = (lane << 8) | m;
        if (k >= MIN_IDX && k < MAX_IDX) local += bin_power(z, k);
    }

    for (int off = 32; off; off >>= 1) local += __shfl_down(local, off);
    if (lane == 0) red[wave] = local;
    __syncthreads();

    if (tid == 0) {
        float S = 0.0f;
        #pragma unroll
        for (int w = 0; w < NTHR / 64; ++w) S += red[w];

        // ref_idx: argmin_k |f[k] - t|, f[k] = k * (10/16384) exact in fp32.
        float tgt = targets[b];
        double kd = (double)tgt * (16384.0 / 10.0);
        int k0 = (int)kd;                       // t>0 so trunc == floor
        const float stepf = 10.0f / 16384.0f;   // exactly representable
        float f0 = (float)k0 * stepf;           // exact products (<=24 bits)
        float f1 = (float)(k0 + 1) * stepf;
        float d0 = fabsf(f0 - tgt);
        float d1 = fabsf(f1 - tgt);
        int r = (d0 <= d1) ? k0 : (k0 + 1);

        float pm1 = bin_power(z, r - 1);
        float p0  = bin_power(z, r);
        float pp1 = bin_power(z, r + 1);
        float other_avg = (S - pm1 - p0 - pp1) * (1.0f / DENOMF);
        row_loss[b] = -10.0f * log10f(p0 / other_avg);
    }
}

__global__ __launch_bounds__(256) void snr_reduce_kernel(
        const float* __restrict__ row_loss, float* __restrict__ out) {
    __shared__ float red[4];
    float s = 0.0f;
    for (int i = threadIdx.x; i < BROWS; i += 256) s += row_loss[i];
    for (int off = 32; off; off >>= 1) s += __shfl_down(s, off);
    if ((threadIdx.x & 63) == 0) red[threadIdx.x >> 6] = s;
    __syncthreads();
    if (threadIdx.x == 0)
        out[0] = (red[0] + red[1] + red[2] + red[3]) * (1.0f / (float)BROWS);
}

extern "C" void kernel_launch(void* const* d_in, const int* in_sizes, int n_in,
                              void* d_out, int out_size, void* d_ws, size_t ws_size,
                              hipStream_t stream) {
    const float* outs    = (const float*)d_in[0];
    const float* targets = (const float*)d_in[1];
    float* ws  = (float*)d_ws;    // 1024 per-row losses
    float* out = (float*)d_out;

    snr_row_kernel<<<BROWS, NTHR, 0, stream>>>(outs, targets, ws);
    snr_reduce_kernel<<<1, 256, 0, stream>>>(ws, out);
}